// Round 1
// baseline (276.894 us; speedup 1.0000x reference)
//
#include <hip/hip_runtime.h>
#include <math.h>

#define VOXSZ 0.04f
#define NV 9
#define NC 24
#define NH 120
#define NW 160

// ---------------------------------------------------------------------------
// ws layout: [0,24): 3 f64 global accumulators (sum_z, sum_z2, n_valid)
//            [24,32): 2 f32 scalars (zmean, zstd)
//            [64, 64+V*H*W*C*4): feats transposed to (V,H,W,C)
// zsum per-voxel is staged in out[n*25+24] and overwritten by znorm pass.
// ---------------------------------------------------------------------------

__global__ void zero_acc_k(double* a) {
  a[0] = 0.0; a[1] = 0.0; a[2] = 0.0;
}

__global__ void transpose_feats_k(const float* __restrict__ in, float* __restrict__ out) {
  int idx = blockIdx.x * blockDim.x + threadIdx.x;
  const int total = NV * NC * NH * NW;
  if (idx >= total) return;
  int w = idx % NW;
  int t = idx / NW;
  int h = t % NH; t /= NH;
  int c = t % NC;
  int v = t / NC;
  out[(((size_t)v * NH + h) * NW + w) * NC + c] = in[idx];
}

template <bool TR>
__global__ __launch_bounds__(256)
void bp_main_k(const int4* __restrict__ coords,
               const float* __restrict__ origin,
               const float* __restrict__ proj,
               const float* __restrict__ feats,
               float* __restrict__ out,
               double* __restrict__ accums,
               int N)
{
  __shared__ float s_proj[NV * 12];
  __shared__ float s_org[3];
  int tid = threadIdx.x;
  if (tid < NV * 12) {
    int v = tid / 12, r = tid % 12;
    s_proj[tid] = proj[v * 16 + r];
  }
  if (tid < 3) s_org[tid] = origin[tid];
  __syncthreads();

  int n = blockIdx.x * blockDim.x + tid;
  float acc[NC];
#pragma unroll
  for (int c = 0; c < NC; ++c) acc[c] = 0.f;
  float zs = 0.f;
  int cnt = 0;

  if (n < N) {
    int4 cd = coords[n];
    float wx = (float)cd.y * VOXSZ + s_org[0];
    float wy = (float)cd.z * VOXSZ + s_org[1];
    float wz = (float)cd.w * VOXSZ + s_org[2];
#pragma unroll
    for (int v = 0; v < NV; ++v) {
      const float* P = &s_proj[v * 12];
      float ix = P[0] * wx + P[1] * wy + P[2]  * wz + P[3];
      float iy = P[4] * wx + P[5] * wy + P[6]  * wz + P[7];
      float iz = P[8] * wx + P[9] * wy + P[10] * wz + P[11];
      float px = ix / iz;
      float py = iy / iz;
      bool inb = (px >= 0.f) && (px <= (float)(NW - 1)) &&
                 (py >= 0.f) && (py <= (float)(NH - 1)) && (iz > 0.f);
      if (!inb) continue;
      cnt++; zs += iz;
      float x0f = floorf(px), y0f = floorf(py);
      float fx1 = px - x0f, fy1 = py - y0f;
      float fx0 = 1.f - fx1, fy0 = 1.f - fy1;
      int x0 = (int)x0f, y0 = (int)y0f;
      // x1==NW only possible when px==NW-1 exactly => fx1==0, so clamping is
      // exact (weight is already 0). Same for y.
      int x1 = (x0 + 1 < NW) ? x0 + 1 : NW - 1;
      int y1 = (y0 + 1 < NH) ? y0 + 1 : NH - 1;
      float w00 = fx0 * fy0, w10 = fx1 * fy0, w01 = fx0 * fy1, w11 = fx1 * fy1;
      if (TR) {
        const float4* p00 = (const float4*)(feats + (((size_t)v * NH + y0) * NW + x0) * NC);
        const float4* p10 = (const float4*)(feats + (((size_t)v * NH + y0) * NW + x1) * NC);
        const float4* p01 = (const float4*)(feats + (((size_t)v * NH + y1) * NW + x0) * NC);
        const float4* p11 = (const float4*)(feats + (((size_t)v * NH + y1) * NW + x1) * NC);
#pragma unroll
        for (int q = 0; q < NC / 4; ++q) {
          float4 f00 = p00[q], f10 = p10[q], f01 = p01[q], f11 = p11[q];
          acc[q * 4 + 0] += f00.x * w00 + f10.x * w10 + f01.x * w01 + f11.x * w11;
          acc[q * 4 + 1] += f00.y * w00 + f10.y * w10 + f01.y * w01 + f11.y * w11;
          acc[q * 4 + 2] += f00.z * w00 + f10.z * w10 + f01.z * w01 + f11.z * w11;
          acc[q * 4 + 3] += f00.w * w00 + f10.w * w10 + f01.w * w01 + f11.w * w11;
        }
      } else {
        const float* base = feats + (size_t)v * NC * NH * NW;
#pragma unroll
        for (int c = 0; c < NC; ++c) {
          const float* pc = base + (size_t)c * NH * NW;
          float f00 = pc[y0 * NW + x0], f10 = pc[y0 * NW + x1];
          float f01 = pc[y1 * NW + x0], f11 = pc[y1 * NW + x1];
          acc[c] += f00 * w00 + f10 * w10 + f01 * w01 + f11 * w11;
        }
      }
    }
  }

  float zsv = 0.f;
  if (n < N) {
    float denom = (cnt > 0) ? (float)cnt : 1.f;
    size_t row = (size_t)n * (NC + 1);
#pragma unroll
    for (int c = 0; c < NC; ++c) out[row + c] = acc[c] / denom;
    zsv = zs / denom;
    out[row + NC] = zsv;                       // temp stage of zsum (col 24)
    out[(size_t)N * (NC + 1) + n] = (float)cnt;  // count output
  }

  // global reductions (f64): sum(zsum*valid), sum(zsum^2*valid), sum(valid)
  double rz = 0.0, rz2 = 0.0, rv = 0.0;
  if (n < N && cnt > 0) {
    rz = (double)zsv;
    rz2 = (double)zsv * (double)zsv;
    rv = 1.0;
  }
#pragma unroll
  for (int off = 32; off > 0; off >>= 1) {
    rz  += __shfl_down(rz,  off, 64);
    rz2 += __shfl_down(rz2, off, 64);
    rv  += __shfl_down(rv,  off, 64);
  }
  if ((tid & 63) == 0) {
    atomicAdd(&accums[0], rz);
    atomicAdd(&accums[1], rz2);
    atomicAdd(&accums[2], rv);
  }
}

__global__ void finalize_k(const double* __restrict__ accums, float* __restrict__ scal) {
  double sz = accums[0], sz2 = accums[1], nv = accums[2];
  double nvm = (nv > 1.0) ? nv : 1.0;          // max(sum(valid), 1)
  double zmean = sz / nvm;
  // sum((zsum-zmean)^2 over valid) = sz2 - 2*zmean*sz + zmean^2*nv
  double var = sz2 - 2.0 * zmean * sz + zmean * zmean * nv;
  if (var < 0.0) var = 0.0;
  double zstd = sqrt(var) + 1e-5;
  scal[0] = (float)zmean;
  scal[1] = (float)zstd;
}

__global__ void znorm_k(const float* __restrict__ scal, float* __restrict__ out, int N) {
  int n = blockIdx.x * blockDim.x + threadIdx.x;
  if (n >= N) return;
  float zmean = scal[0], zstd = scal[1];
  size_t row = (size_t)n * (NC + 1);
  float zsv = out[row + NC];
  float cntf = out[(size_t)N * (NC + 1) + n];
  out[row + NC] = (cntf > 0.f) ? (zsv - zmean) / zstd : 0.f;
}

extern "C" void kernel_launch(void* const* d_in, const int* in_sizes, int n_in,
                              void* d_out, int out_size, void* d_ws, size_t ws_size,
                              hipStream_t stream) {
  const int4*  coords = (const int4*)d_in[0];
  const float* origin = (const float*)d_in[1];
  const float* feats  = (const float*)d_in[2];
  const float* proj   = (const float*)d_in[3];
  float* out = (float*)d_out;
  int N = in_sizes[0] / 4;

  const size_t FT = (size_t)NV * NH * NW * NC;  // transposed feats element count
  char* ws = (char*)d_ws;
  double* accums = (double*)ws;                      // 3 doubles
  float*  scal   = (float*)(ws + 3 * sizeof(double)); // 2 floats
  float*  featsT = (float*)(ws + 64);                 // 16B-aligned

  bool use_tr = (ws_size >= 64 + FT * sizeof(float));

  zero_acc_k<<<1, 1, 0, stream>>>(accums);
  int blocks = (N + 255) / 256;
  if (use_tr) {
    transpose_feats_k<<<(int)((FT + 255) / 256), 256, 0, stream>>>(feats, featsT);
    bp_main_k<true><<<blocks, 256, 0, stream>>>(coords, origin, proj, featsT, out, accums, N);
  } else {
    bp_main_k<false><<<blocks, 256, 0, stream>>>(coords, origin, proj, feats, out, accums, N);
  }
  finalize_k<<<1, 1, 0, stream>>>(accums, scal);
  znorm_k<<<blocks, 256, 0, stream>>>(scal, out, N);
}